// Round 1
// baseline (197.040 us; speedup 1.0000x reference)
//
#include <hip/hip_runtime.h>

#define D_IN   784
#define HDIM   512
#define BATCH_N 1024
#define TCH    16
#define NCHUNK (D_IN / TCH)   // 49

__device__ __forceinline__ float relu_(float v) { return fmaxf(v, 0.0f); }

// ---------------------------------------------------------------------------
// Transpose in_W [H][D] -> wT [D][H] so the scan kernel reads contiguous rows.
// Writes coalesced; reads strided (1.6 MB, L2/L3 absorbs).
// ---------------------------------------------------------------------------
__global__ __launch_bounds__(256, 1)
void transpose_inW(const float* __restrict__ inW, float* __restrict__ wT) {
    int idx = blockIdx.x * 256 + threadIdx.x;
    if (idx < D_IN * HDIM) {
        int i = idx / HDIM;
        int h = idx - i * HDIM;
        wT[idx] = inW[(size_t)h * D_IN + i];
    }
}

// ---------------------------------------------------------------------------
// One wave (64 lanes) per batch row. Lane l owns hidden units [8l, 8l+8).
// Chunked over TCH=16 scan steps: per-lane partial dots accumulate, then all
// 16 cross-lane reductions are done together (pipelined butterflies).
// ---------------------------------------------------------------------------
template<bool USE_WT>
__global__ __launch_bounds__(64, 1)
void nade_fwd(const float* __restrict__ x,      // [B][D]
              const float* __restrict__ in_W,   // [H][D]   (used when !USE_WT)
              const float* __restrict__ in_b,   // [H]
              const float* __restrict__ hW,     // [D][H]
              const float* __restrict__ h_b,    // [D]
              const float* __restrict__ wT,     // [D][H]   (used when USE_WT)
              float* __restrict__ out)          // [B][D]
{
    const int b  = blockIdx.x;
    const int l  = threadIdx.x;     // 0..63
    const int h0 = l * 8;

    // accumulator a[h0..h0+7] = in_b
    float a[8];
    {
        float4 b0 = *(const float4*)(in_b + h0);
        float4 b1 = *(const float4*)(in_b + h0 + 4);
        a[0] = b0.x; a[1] = b0.y; a[2] = b0.z; a[3] = b0.w;
        a[4] = b1.x; a[5] = b1.y; a[6] = b1.z; a[7] = b1.w;
    }

    const float* xrow = x   + (size_t)b * D_IN;
    float*       orow = out + (size_t)b * D_IN;

    for (int c = 0; c < NCHUNK; ++c) {
        const int i0 = c * TCH;

        // x chunk (binarized values; same across lanes)
        float xs[TCH];
        #pragma unroll
        for (int q = 0; q < TCH / 4; ++q) {
            float4 v = *(const float4*)(xrow + i0 + 4 * q);
            xs[4*q+0] = v.x; xs[4*q+1] = v.y; xs[4*q+2] = v.z; xs[4*q+3] = v.w;
        }

        float partial[TCH];

        #pragma unroll
        for (int t = 0; t < TCH; ++t) {
            const int i = i0 + t;

            // dot( relu(a), h_W[i, h0:h0+8] )  -- uses a BEFORE the update
            const float4 hw0 = *(const float4*)(hW + (size_t)i * HDIM + h0);
            const float4 hw1 = *(const float4*)(hW + (size_t)i * HDIM + h0 + 4);
            float p;
            p = relu_(a[0]) * hw0.x;
            p = fmaf(relu_(a[1]), hw0.y, p);
            p = fmaf(relu_(a[2]), hw0.z, p);
            p = fmaf(relu_(a[3]), hw0.w, p);
            p = fmaf(relu_(a[4]), hw1.x, p);
            p = fmaf(relu_(a[5]), hw1.y, p);
            p = fmaf(relu_(a[6]), hw1.z, p);
            p = fmaf(relu_(a[7]), hw1.w, p);
            partial[t] = p;

            // rank-1 update: a += x_i * in_W[:, i]   (skip when x_i == 0)
            const float xi = xs[t];
            if (xi != 0.0f) {
                float4 w0, w1;
                if (USE_WT) {
                    w0 = *(const float4*)(wT + (size_t)i * HDIM + h0);
                    w1 = *(const float4*)(wT + (size_t)i * HDIM + h0 + 4);
                } else {
                    w0.x = in_W[(size_t)(h0+0) * D_IN + i];
                    w0.y = in_W[(size_t)(h0+1) * D_IN + i];
                    w0.z = in_W[(size_t)(h0+2) * D_IN + i];
                    w0.w = in_W[(size_t)(h0+3) * D_IN + i];
                    w1.x = in_W[(size_t)(h0+4) * D_IN + i];
                    w1.y = in_W[(size_t)(h0+5) * D_IN + i];
                    w1.z = in_W[(size_t)(h0+6) * D_IN + i];
                    w1.w = in_W[(size_t)(h0+7) * D_IN + i];
                }
                a[0] = fmaf(xi, w0.x, a[0]);
                a[1] = fmaf(xi, w0.y, a[1]);
                a[2] = fmaf(xi, w0.z, a[2]);
                a[3] = fmaf(xi, w0.w, a[3]);
                a[4] = fmaf(xi, w1.x, a[4]);
                a[5] = fmaf(xi, w1.y, a[5]);
                a[6] = fmaf(xi, w1.z, a[6]);
                a[7] = fmaf(xi, w1.w, a[7]);
            }
        }

        // 16 cross-lane reductions, pipelined (independent across t)
        #pragma unroll
        for (int s = 1; s < 64; s <<= 1) {
            #pragma unroll
            for (int t = 0; t < TCH; ++t)
                partial[t] += __shfl_xor(partial[t], s, 64);
        }

        // sigmoid (all lanes compute redundantly; statically indexed)
        float hb[TCH];
        #pragma unroll
        for (int q = 0; q < TCH / 4; ++q) {
            float4 v = *(const float4*)(h_b + i0 + 4 * q);
            hb[4*q+0] = v.x; hb[4*q+1] = v.y; hb[4*q+2] = v.z; hb[4*q+3] = v.w;
        }
        float r[TCH];
        #pragma unroll
        for (int t = 0; t < TCH; ++t) {
            float s = partial[t] + hb[t];
            r[t] = 1.0f / (1.0f + __expf(-s));
        }

        // lane 0 stores the 16 outputs for this chunk
        if (l == 0) {
            #pragma unroll
            for (int q = 0; q < TCH / 4; ++q) {
                float4 v = make_float4(r[4*q+0], r[4*q+1], r[4*q+2], r[4*q+3]);
                *(float4*)(orow + i0 + 4 * q) = v;
            }
        }
    }
}

extern "C" void kernel_launch(void* const* d_in, const int* in_sizes, int n_in,
                              void* d_out, int out_size, void* d_ws, size_t ws_size,
                              hipStream_t stream) {
    const float* x    = (const float*)d_in[0];
    const float* in_W = (const float*)d_in[1];
    const float* in_b = (const float*)d_in[2];
    const float* hW   = (const float*)d_in[3];
    const float* h_b  = (const float*)d_in[4];
    float* out = (float*)d_out;

    const size_t need = (size_t)D_IN * HDIM * sizeof(float);
    if (ws_size >= need) {
        float* wT = (float*)d_ws;
        hipLaunchKernelGGL(transpose_inW,
                           dim3((D_IN * HDIM + 255) / 256), dim3(256), 0, stream,
                           in_W, wT);
        hipLaunchKernelGGL((nade_fwd<true>),
                           dim3(BATCH_N), dim3(64), 0, stream,
                           x, in_W, in_b, hW, h_b, wT, out);
    } else {
        hipLaunchKernelGGL((nade_fwd<false>),
                           dim3(BATCH_N), dim3(64), 0, stream,
                           x, in_W, in_b, hW, h_b, (const float*)nullptr, out);
    }
}

// Round 2
// 133.393 us; speedup vs baseline: 1.4771x; 1.4771x over previous
//
#include <hip/hip_runtime.h>

#define D_IN    784
#define HDIM    512
#define BATCH_N 1024
#define TCH     8
#define NCH     (D_IN / TCH)     // 98
#define CHW     (TCH * HDIM)     // 4096 floats per chunk per matrix

__device__ __forceinline__ float relu_(float v) { return fmaxf(v, 0.0f); }

// ---------------------------------------------------------------------------
// Transpose in_W [H][D] -> wT [D][H]
// ---------------------------------------------------------------------------
__global__ __launch_bounds__(256, 1)
void transpose_inW(const float* __restrict__ inW, float* __restrict__ wT) {
    int idx = blockIdx.x * 256 + threadIdx.x;
    if (idx < D_IN * HDIM) {
        int i = idx / HDIM;
        int h = idx - i * HDIM;
        wT[idx] = inW[(size_t)h * D_IN + i];
    }
}

__device__ __forceinline__ void load8(float (&d)[8], const float* p) {
    float4 v0 = *(const float4*)(p);
    float4 v1 = *(const float4*)(p + 4);
    d[0]=v0.x; d[1]=v0.y; d[2]=v0.z; d[3]=v0.w;
    d[4]=v1.x; d[5]=v1.y; d[6]=v1.z; d[7]=v1.w;
}

// Per-wave async stage of its slice of one chunk (both matrices) into LDS.
// waves 0,1 stage hW halves; waves 2,3 stage wT halves. 8 issues x 1KB each.
__device__ __forceinline__ void stage_chunk(const float* __restrict__ hW,
                                            const float* __restrict__ wT,
                                            float* dhw, float* dwt,
                                            int i0, int w, int l) {
    const float* src = (w < 2) ? (hW + (size_t)i0 * HDIM + w * 2048)
                               : (wT + (size_t)i0 * HDIM + (w - 2) * 2048);
    float* dst = (w < 2) ? (dhw + w * 2048) : (dwt + (w - 2) * 2048);
    #pragma unroll
    for (int j = 0; j < 8; ++j) {
        __builtin_amdgcn_global_load_lds(
            (const __attribute__((address_space(1))) void*)(src + j * 256 + l * 4),
            (__attribute__((address_space(3))) void*)(dst + j * 256 + l * 4),
            16, 0, 0);
    }
}

// Compute one 8-step chunk entirely from LDS-staged weights.
// Lane l owns hidden units {4l..4l+3} U {256+4l..256+4l+3}.
__device__ __forceinline__ void compute_chunk(const float* __restrict__ bhw,
                                              const float* __restrict__ bwt,
                                              const float (&xs)[8],
                                              const float (&hb)[8],
                                              float (&a)[8],
                                              float* __restrict__ sp,   // per-wave 512-float LDS scratch
                                              float* __restrict__ orow,
                                              int i0, int l) {
    float part[TCH];
    #pragma unroll
    for (int t = 0; t < TCH; ++t) {
        const float* hp = bhw + t * HDIM;
        float4 hw0 = *(const float4*)(hp + 4 * l);
        float4 hw1 = *(const float4*)(hp + 256 + 4 * l);
        float init = (l == 0) ? hb[t] : 0.0f;
        float p0 = fmaf(relu_(a[0]), hw0.x, init);
        p0 = fmaf(relu_(a[1]), hw0.y, p0);
        p0 = fmaf(relu_(a[2]), hw0.z, p0);
        p0 = fmaf(relu_(a[3]), hw0.w, p0);
        float p1 = relu_(a[4]) * hw1.x;
        p1 = fmaf(relu_(a[5]), hw1.y, p1);
        p1 = fmaf(relu_(a[6]), hw1.z, p1);
        p1 = fmaf(relu_(a[7]), hw1.w, p1);
        part[t] = p0 + p1;

        const float* wp = bwt + t * HDIM;
        float4 w0 = *(const float4*)(wp + 4 * l);
        float4 w1 = *(const float4*)(wp + 256 + 4 * l);
        const float xi = xs[t];   // exactly 0.0 or 1.0 -> unconditional FMA is exact
        a[0] = fmaf(xi, w0.x, a[0]); a[1] = fmaf(xi, w0.y, a[1]);
        a[2] = fmaf(xi, w0.z, a[2]); a[3] = fmaf(xi, w0.w, a[3]);
        a[4] = fmaf(xi, w1.x, a[4]); a[5] = fmaf(xi, w1.y, a[5]);
        a[6] = fmaf(xi, w1.z, a[6]); a[7] = fmaf(xi, w1.w, a[7]);
    }

    // Reduction: per-wave LDS transpose P[t][l], then 8-lane groups finish.
    #pragma unroll
    for (int t = 0; t < TCH; ++t) sp[t * 64 + l] = part[t];

    const int t = l >> 3;        // 0..7 : which output this 8-lane group owns
    const int c = l & 7;
    const float* pr = sp + t * 64 + c * 8;
    float4 q0 = *(const float4*)(pr);
    float4 q1 = *(const float4*)(pr + 4);
    float v = ((q0.x + q0.y) + (q0.z + q0.w)) + ((q1.x + q1.y) + (q1.z + q1.w));
    v += __shfl_xor(v, 1, 64);
    v += __shfl_xor(v, 2, 64);
    v += __shfl_xor(v, 4, 64);
    float r = __builtin_amdgcn_rcpf(1.0f + __expf(-v));
    if ((l & 7) == 0) orow[i0 + t] = r;
}

__global__ __launch_bounds__(256, 1)
void nade_fwd2(const float* __restrict__ x,
               const float* __restrict__ in_b,
               const float* __restrict__ hW,
               const float* __restrict__ h_b,
               const float* __restrict__ wT,
               float* __restrict__ out) {
    __shared__ float s_hw[2][CHW];
    __shared__ float s_wt[2][CHW];
    __shared__ float s_p[4 * 512];

    const int tid = threadIdx.x;
    const int w = tid >> 6;      // wave 0..3 -> batch row
    const int l = tid & 63;
    const int row = blockIdx.x * 4 + w;

    float a[8];
    {
        float4 b0 = *(const float4*)(in_b + 4 * l);
        float4 b1 = *(const float4*)(in_b + 256 + 4 * l);
        a[0]=b0.x; a[1]=b0.y; a[2]=b0.z; a[3]=b0.w;
        a[4]=b1.x; a[5]=b1.y; a[6]=b1.z; a[7]=b1.w;
    }

    const float* xrow = x + (size_t)row * D_IN;
    float* orow = out + (size_t)row * D_IN;
    float* sp = s_p + w * 512;

    float xsA[8], xsB[8], hbA[8], hbB[8];
    load8(xsA, xrow);
    load8(hbA, h_b);

    stage_chunk(hW, wT, s_hw[0], s_wt[0], 0, w, l);
    __syncthreads();   // drains vmcnt(0): buf0 staged

    for (int cc = 0; cc < NCH / 2; ++cc) {
        const int c = 2 * cc;

        // phase A: stage c+1 -> buf1, prefetch x/hb for c+1, compute c from buf0
        stage_chunk(hW, wT, s_hw[1], s_wt[1], (c + 1) * TCH, w, l);
        load8(xsB, xrow + (c + 1) * TCH);
        load8(hbB, h_b + (c + 1) * TCH);
        compute_chunk(s_hw[0], s_wt[0], xsA, hbA, a, sp, orow, c * TCH, l);
        __syncthreads();

        // phase B: stage c+2 -> buf0 (last pair skips), compute c+1 from buf1
        if (c + 2 < NCH) {
            stage_chunk(hW, wT, s_hw[0], s_wt[0], (c + 2) * TCH, w, l);
            load8(xsA, xrow + (c + 2) * TCH);
            load8(hbA, h_b + (c + 2) * TCH);
        }
        compute_chunk(s_hw[1], s_wt[1], xsB, hbB, a, sp, orow, (c + 1) * TCH, l);
        __syncthreads();
    }
}

// ---------------------------------------------------------------------------
// Fallback (no workspace): round-1 kernel, strided in_W reads.
// ---------------------------------------------------------------------------
__global__ __launch_bounds__(64, 1)
void nade_fwd_fallback(const float* __restrict__ x,
                       const float* __restrict__ in_W,
                       const float* __restrict__ in_b,
                       const float* __restrict__ hW,
                       const float* __restrict__ h_b,
                       float* __restrict__ out) {
    const int b  = blockIdx.x;
    const int l  = threadIdx.x;
    const int h0 = l * 8;

    float a[8];
    {
        float4 b0 = *(const float4*)(in_b + h0);
        float4 b1 = *(const float4*)(in_b + h0 + 4);
        a[0]=b0.x; a[1]=b0.y; a[2]=b0.z; a[3]=b0.w;
        a[4]=b1.x; a[5]=b1.y; a[6]=b1.z; a[7]=b1.w;
    }
    const float* xrow = x + (size_t)b * D_IN;
    float* orow = out + (size_t)b * D_IN;

    for (int i = 0; i < D_IN; ++i) {
        const float4 hw0 = *(const float4*)(hW + (size_t)i * HDIM + h0);
        const float4 hw1 = *(const float4*)(hW + (size_t)i * HDIM + h0 + 4);
        float p;
        p = relu_(a[0]) * hw0.x;
        p = fmaf(relu_(a[1]), hw0.y, p);
        p = fmaf(relu_(a[2]), hw0.z, p);
        p = fmaf(relu_(a[3]), hw0.w, p);
        p = fmaf(relu_(a[4]), hw1.x, p);
        p = fmaf(relu_(a[5]), hw1.y, p);
        p = fmaf(relu_(a[6]), hw1.z, p);
        p = fmaf(relu_(a[7]), hw1.w, p);
        #pragma unroll
        for (int s = 1; s < 64; s <<= 1) p += __shfl_xor(p, s, 64);
        if (l == 0) orow[i] = 1.0f / (1.0f + __expf(-(p + h_b[i])));

        const float xi = xrow[i];
        if (xi != 0.0f) {
            a[0] = fmaf(xi, in_W[(size_t)(h0+0)*D_IN + i], a[0]);
            a[1] = fmaf(xi, in_W[(size_t)(h0+1)*D_IN + i], a[1]);
            a[2] = fmaf(xi, in_W[(size_t)(h0+2)*D_IN + i], a[2]);
            a[3] = fmaf(xi, in_W[(size_t)(h0+3)*D_IN + i], a[3]);
            a[4] = fmaf(xi, in_W[(size_t)(h0+4)*D_IN + i], a[4]);
            a[5] = fmaf(xi, in_W[(size_t)(h0+5)*D_IN + i], a[5]);
            a[6] = fmaf(xi, in_W[(size_t)(h0+6)*D_IN + i], a[6]);
            a[7] = fmaf(xi, in_W[(size_t)(h0+7)*D_IN + i], a[7]);
        }
    }
}

extern "C" void kernel_launch(void* const* d_in, const int* in_sizes, int n_in,
                              void* d_out, int out_size, void* d_ws, size_t ws_size,
                              hipStream_t stream) {
    const float* x    = (const float*)d_in[0];
    const float* in_W = (const float*)d_in[1];
    const float* in_b = (const float*)d_in[2];
    const float* hW   = (const float*)d_in[3];
    const float* h_b  = (const float*)d_in[4];
    float* out = (float*)d_out;

    const size_t need = (size_t)D_IN * HDIM * sizeof(float);
    if (ws_size >= need) {
        float* wT = (float*)d_ws;
        hipLaunchKernelGGL(transpose_inW,
                           dim3((D_IN * HDIM + 255) / 256), dim3(256), 0, stream,
                           in_W, wT);
        hipLaunchKernelGGL(nade_fwd2,
                           dim3(BATCH_N / 4), dim3(256), 0, stream,
                           x, in_b, hW, h_b, wT, out);
    } else {
        hipLaunchKernelGGL(nade_fwd_fallback,
                           dim3(BATCH_N), dim3(64), 0, stream,
                           x, in_W, in_b, hW, h_b, out);
    }
}